// Round 13
// baseline (423.949 us; speedup 1.0000x reference)
//
#include <hip/hip_runtime.h>
#include <math.h>

#define B_ 64
#define S_ 2048
#define H_ 1024
#define K_ 1024
#define M_ (B_*S_)   // 131072 rows of the big GEMM

using f32x4   = __attribute__((ext_vector_type(4))) float;
using bf16x8  = __attribute__((ext_vector_type(8))) __bf16;

__device__ __forceinline__ unsigned short f2b(float f) {
  unsigned int u = __float_as_uint(f);
  u += 0x7fffu + ((u >> 16) & 1u);   // RNE
  return (unsigned short)(u >> 16);
}

// tanh(x) = (e^2x - 1)/(e^2x + 1); clamp so t stays finite (tanh saturated anyway)
__device__ __forceinline__ float fast_tanh(float x) {
  float xc = fminf(fmaxf(x, -15.f), 15.f);
  float t = __expf(2.f * xc);
  return (t - 1.f) * __builtin_amdgcn_rcpf(t + 1.f);
}

typedef __attribute__((address_space(1))) void gvoid_t;
typedef __attribute__((address_space(3))) void lvoid_t;

__device__ __forceinline__ void async16(const void* g, void* l) {
  __builtin_amdgcn_global_load_lds((gvoid_t*)g, (lvoid_t*)l, 16, 0, 0);
}

// A f32 [128][32]: 8 chunks of 16B per row; chunk' = chunk ^ (r&7)  (R10/R11-proven)
__device__ __forceinline__ int swzf(int r, int chunk) {
  return r * 32 + ((chunk ^ (r & 7)) << 2);   // f32 elements
}
// B bf16 [128][32]: 4 slots of 16B per row; slot' = sl ^ ((r>>1)&3)  (R2-proven)
__device__ __forceinline__ int swz(int r, int sl) {
  return r * 32 + ((sl ^ ((r >> 1) & 3)) << 3);
}

// mask decode shared by all mask readers
__device__ __forceinline__ bool mask_at(const void* mask, int fl, int idx) {
  if (fl == 1)      return ((const unsigned char*)mask)[idx] != 0;
  else if (fl == 2) return ((const float*)mask)[idx] != 0.f;
  else              return ((const int*)mask)[idx] != 0;
}

// misc layout (ints): [0]=flag [1]=Mp [2]=Mpr(128-rounded)
//                     [16..144)=blocksum  [144..272]=blockoff (272 = Mp sentinel)

// ---------------------------------------------------------------- mask dtype
__global__ void detect_mask(const unsigned int* __restrict__ m, int* __restrict__ misc) {
  __shared__ int red[256];
  int t = threadIdx.x;
  int f = 0;
  for (int i = 0; i < 32; ++i) {
    unsigned int w = m[t * 32 + i];
    if (w > 1u) f |= 1;
    if (w != 0u && w != 0x3f800000u) f |= 2;
  }
  red[t] = f;
  __syncthreads();
  for (int o = 128; o > 0; o >>= 1) { if (t < o) red[t] |= red[t + o]; __syncthreads(); }
  if (t == 0) {
    int g = red[0];
    misc[0] = ((g & 1) == 0) ? 0 : (((g & 2) == 0) ? 2 : 1);
  }
}

// ---------------------------------------------------------------- compaction scans
__global__ void mask_count(const void* __restrict__ mask, int* __restrict__ misc) {
  __shared__ int red[256];
  const int fl = misc[0];
  const int t = threadIdx.x, blk = blockIdx.x;
  int cnt = 0;
#pragma unroll
  for (int i = 0; i < 4; ++i)
    cnt += mask_at(mask, fl, blk * 1024 + t * 4 + i) ? 0 : 1;
  red[t] = cnt; __syncthreads();
  for (int o = 128; o > 0; o >>= 1) { if (t < o) red[t] += red[t + o]; __syncthreads(); }
  if (t == 0) misc[16 + blk] = red[0];
}

__global__ void mask_scan(int* __restrict__ misc) {
  if (threadIdx.x == 0) {
    int acc = 0;
    for (int i = 0; i < 128; ++i) { misc[144 + i] = acc; acc += misc[16 + i]; }
    misc[144 + 128] = acc;    // sentinel: end of batch 63
    misc[1] = acc;
    misc[2] = (acc + 127) & ~127;
  }
}

__global__ void mask_writeidx(const void* __restrict__ mask, const int* __restrict__ misc,
                              int* __restrict__ ridx) {
  __shared__ int sc[256];
  const int fl = misc[0];
  const int t = threadIdx.x, blk = blockIdx.x;
  int um[4]; int cnt = 0;
#pragma unroll
  for (int i = 0; i < 4; ++i) {
    um[i] = mask_at(mask, fl, blk * 1024 + t * 4 + i) ? 0 : 1;
    cnt += um[i];
  }
  sc[t] = cnt; __syncthreads();
  for (int o = 1; o < 256; o <<= 1) {
    int v = (t >= o) ? sc[t - o] : 0;
    __syncthreads();
    sc[t] += v;
    __syncthreads();
  }
  int base = misc[144 + blk] + sc[t] - cnt;   // exclusive prefix
#pragma unroll
  for (int i = 0; i < 4; ++i)
    if (um[i]) ridx[base++] = blk * 1024 + t * 4 + i;
}

// ---------------------------------------------------------------- Wk -> bf16
__global__ void convert_wk(const float* __restrict__ src, unsigned short* __restrict__ dst) {
  int i = blockIdx.x * blockDim.x + threadIdx.x;
  float4 v = ((const float4*)src)[i];
  ushort4 o;
  o.x = f2b(v.x); o.y = f2b(v.y); o.z = f2b(v.z); o.w = f2b(v.w);
  *(ushort4*)(dst + (size_t)i * 4) = o;
}

// ---------------------------------------------------------------- qp = query @ Wq.T
__global__ void qp_kernel(const float* __restrict__ query, const float* __restrict__ Wq,
                          float* __restrict__ qp) {
  __shared__ float qs[1024];
  const int b = blockIdx.y, q4b = blockIdx.x, t = threadIdx.x;
  ((float4*)qs)[t] = ((const float4*)(query + b * 1024))[t];
  __syncthreads();
  const int h = q4b * 256 + t;
  const float4* wr = (const float4*)(Wq + (size_t)h * 1024);
  float s = 0.f;
#pragma unroll 4
  for (int q4 = 0; q4 < 256; ++q4) {
    float4 w = wr[q4];
    float4 q = ((const float4*)qs)[q4];
    s += w.x * q.x + w.y * q.y + w.z * q.z + w.w * q.w;
  }
  qp[b * 1024 + h] = s;
}

// ---------------------------------------------------------------- GEMM+energy: gather f32 A,
// BK=32, DOUBLE-BUFFERED LDS, prefetch-before-compute, ONE barrier per K-step.
// (T3 minimal 2-phase: STAGE(next) issued before compute(cur) so HBM latency of
// the A-gather hides under ds_read+MFMA; __syncthreads drains it after.)
__global__ __launch_bounds__(256, 3) void gemm_energy_g(
    const float* __restrict__ keys,          // [M_][1024] f32 (original)
    const __bf16* __restrict__ wk,           // [1024][1024] bf16 Wk
    const float* __restrict__ qp,            // [64][1024]
    const float* __restrict__ v,             // [1024]
    float* __restrict__ energy,              // [M_] (original row ids)
    const int* __restrict__ misc,
    const int* __restrict__ ridx) {
  __shared__ __align__(16) float  Asf[2][128 * 32];   // 2 x 16 KB
  __shared__ __align__(16) __bf16 Bs[2][128 * 32];    // 2 x  8 KB

  const int tid  = threadIdx.x;
  const int w    = tid >> 6;
  const int lane = tid & 63;

  // XCD mapping (R9-proven): all 8 n-tiles of an m-tile on one XCD; working
  // m-tiles spread over all XCDs regardless of compact count.
  const int orig = blockIdx.x;                   // 0..8191
  const int x = orig & 7, j = orig >> 3;
  const int m0 = (x + 8 * (j >> 3)) * 128;
  const int n0 = (j & 7) * 128;

  const int mpr = misc[2];
  const int mp  = misc[1];
  if (m0 >= mpr || mp == 0) return;

  const int wm = w >> 1, wn = w & 1;

  f32x4 acc[4][4] = {};

  // A staging: [128][32] f32 = 1024 chunks of 16B; this thread owns 4 (gathered rows).
  const float* asrc[4]; int adst[4];
#pragma unroll
  for (int i = 0; i < 4; ++i) {
    int c = tid + i * 256;
    int r = c >> 3, cl = c & 7;
    int row = m0 + r;
    int oro = (row < mp) ? ridx[row] : ridx[mp - 1];   // clamp: pads discarded later
    asrc[i] = keys + (size_t)oro * K_ + ((cl ^ (r & 7)) << 2);
    adst[i] = (i * 256 + w * 64) * 4;
  }
  // B staging: [128][32] bf16 = 512 chunks of 16B; this thread owns 2.
  const __bf16* bsrc[2]; int bdst[2];
#pragma unroll
  for (int jj = 0; jj < 2; ++jj) {
    int c = tid + jj * 256;
    int r = c >> 2;
    int soff = (((c & 3) ^ ((r >> 1) & 3)) << 3);
    bsrc[jj] = wk + (size_t)(n0 + r) * K_ + soff;
    bdst[jj] = (jj * 256 + w * 64) * 8;
  }

  // prologue: stage k-tile 0 into buffer 0
#pragma unroll
  for (int i = 0; i < 4; ++i) async16(asrc[i], &Asf[0][adst[i]]);
#pragma unroll
  for (int jj = 0; jj < 2; ++jj) async16(bsrc[jj], &Bs[0][bdst[jj]]);
  __syncthreads();

  for (int kt = 0; kt < 32; ++kt) {
    const int cur = kt & 1, nxt = cur ^ 1;
    // phase 1: issue next tile's stage (latency hides under compute below)
    if (kt + 1 < 32) {
      const int k1 = (kt + 1) * 32;
#pragma unroll
      for (int i = 0; i < 4; ++i) async16(asrc[i] + k1, &Asf[nxt][adst[i]]);
#pragma unroll
      for (int jj = 0; jj < 2; ++jj) async16(bsrc[jj] + k1, &Bs[nxt][bdst[jj]]);
    }
    // phase 2: compute current tile
    const int g = lane >> 4;
    bf16x8 af[4], bfr[4];
#pragma unroll
    for (int mi = 0; mi < 4; ++mi) {
      int r = wm * 64 + mi * 16 + (lane & 15);
      int e = swzf(r, 2 * g);
      f32x4 lo = *(const f32x4*)(&Asf[cur][e]);
      f32x4 hi = *(const f32x4*)(&Asf[cur][swzf(r, 2 * g + 1)]);
      bf16x8 u;
      u[0] = (__bf16)lo[0]; u[1] = (__bf16)lo[1]; u[2] = (__bf16)lo[2]; u[3] = (__bf16)lo[3];
      u[4] = (__bf16)hi[0]; u[5] = (__bf16)hi[1]; u[6] = (__bf16)hi[2]; u[7] = (__bf16)hi[3];
      af[mi] = u;
    }
#pragma unroll
    for (int ni = 0; ni < 4; ++ni) {
      int r = wn * 64 + ni * 16 + (lane & 15);
      bfr[ni] = *(const bf16x8*)(&Bs[cur][swz(r, g)]);
    }
#pragma unroll
    for (int mi = 0; mi < 4; ++mi)
#pragma unroll
      for (int ni = 0; ni < 4; ++ni)
        acc[mi][ni] = __builtin_amdgcn_mfma_f32_16x16x32_bf16(af[mi], bfr[ni], acc[mi][ni], 0, 0, 0);
    // one barrier per K-step: drains next-tile loads + fences cur-buffer reuse
    __syncthreads();
  }

  // epilogue with ridx indirection
  float vv[4]; int hh[4];
#pragma unroll
  for (int ni = 0; ni < 4; ++ni) {
    hh[ni] = n0 + wn * 64 + ni * 16 + (lane & 15);
    vv[ni] = v[hh[ni]];
  }
#pragma unroll
  for (int mi = 0; mi < 4; ++mi) {
    const int rowbase = m0 + wm * 64 + mi * 16 + (lane >> 4) * 4;
    int oro[4];
#pragma unroll
    for (int rr = 0; rr < 4; ++rr) {
      int row = rowbase + rr;
      oro[rr] = (row < mp) ? ridx[row] : -1;
    }
    float ps[4] = {0.f, 0.f, 0.f, 0.f};
#pragma unroll
    for (int ni = 0; ni < 4; ++ni)
#pragma unroll
      for (int rr = 0; rr < 4; ++rr) {
        int bb = (oro[rr] >= 0 ? oro[rr] : 0) >> 11;
        ps[rr] += fast_tanh(acc[mi][ni][rr] + qp[bb * H_ + hh[ni]]) * vv[ni];
      }
#pragma unroll
    for (int off = 1; off < 16; off <<= 1)
#pragma unroll
      for (int rr = 0; rr < 4; ++rr)
        ps[rr] += __shfl_xor(ps[rr], off, 64);
    if ((lane & 15) == 0) {
#pragma unroll
      for (int rr = 0; rr < 4; ++rr)
        if (oro[rr] >= 0) atomicAdd(&energy[oro[rr]], ps[rr]);
    }
  }
}

// ---------------------------------------------------------------- fallback GEMM (f32 keys, full M)
__global__ __launch_bounds__(256) void gemm_energy(
    const float* __restrict__ keys, const __bf16* __restrict__ wk,
    const float* __restrict__ qp, const float* __restrict__ v,
    float* __restrict__ energy) {
  __shared__ __align__(16) __bf16 As[128 * 32];
  __shared__ __align__(16) __bf16 Bs[128 * 32];

  const int tid  = threadIdx.x;
  const int w    = tid >> 6;
  const int lane = tid & 63;

  const int orig = blockIdx.x;
  const int wgid = (orig & 7) * 1024 + (orig >> 3);
  const int m0 = (wgid >> 3) * 128;
  const int n0 = (wgid & 7) * 128;

  const int wm = w >> 1, wn = w & 1;

  f32x4 acc[4][4] = {};

  int arow[2], aslot[2];
#pragma unroll
  for (int i = 0; i < 2; ++i) {
    int c = tid + i * 256;
    arow[i]  = c >> 2;
    aslot[i] = c & 3;
  }
  const float* Abase = keys + (size_t)m0 * K_;

  int brow[2], bs_src[2], bs_dst[2];
#pragma unroll
  for (int j = 0; j < 2; ++j) {
    int flat = w * 1024 + j * 512 + lane * 8;
    brow[j]   = flat >> 5;
    bs_src[j] = (((flat >> 3) & 3) ^ ((brow[j] >> 1) & 3)) * 8;
    bs_dst[j] = w * 1024 + j * 512;
  }

  float4 pre[2][2];
#pragma unroll
  for (int i = 0; i < 2; ++i) {
    const float* p = Abase + arow[i] * K_ + aslot[i] * 8;
    pre[i][0] = *(const float4*)p;
    pre[i][1] = *(const float4*)(p + 4);
  }

  for (int kt = 0; kt < 32; ++kt) {
    const int k0 = kt * 32;
#pragma unroll
    for (int i = 0; i < 2; ++i) {
      bf16x8 u;
      u[0] = (__bf16)pre[i][0].x; u[1] = (__bf16)pre[i][0].y;
      u[2] = (__bf16)pre[i][0].z; u[3] = (__bf16)pre[i][0].w;
      u[4] = (__bf16)pre[i][1].x; u[5] = (__bf16)pre[i][1].y;
      u[6] = (__bf16)pre[i][1].z; u[7] = (__bf16)pre[i][1].w;
      *(bf16x8*)(&As[swz(arow[i], aslot[i])]) = u;
    }
#pragma unroll
    for (int j = 0; j < 2; ++j)
      async16(wk + (size_t)(n0 + brow[j]) * K_ + k0 + bs_src[j], &Bs[bs_dst[j]]);
    __syncthreads();
    if (kt + 1 < 32) {
#pragma unroll
      for (int i = 0; i < 2; ++i) {
        const float* p = Abase + arow[i] * K_ + (k0 + 32) + aslot[i] * 8;
        pre[i][0] = *(const float4*)p;
        pre[i][1] = *(const float4*)(p + 4);
      }
    }
    const int g = lane >> 4;
    bf16x8 af[4], bfr[4];
#pragma unroll
    for (int mi = 0; mi < 4; ++mi) {
      int r = wm * 64 + mi * 16 + (lane & 15);
      af[mi] = *(const bf16x8*)(&As[swz(r, g)]);
    }
#pragma unroll
    for (int ni = 0; ni < 4; ++ni) {
      int r = wn * 64 + ni * 16 + (lane & 15);
      bfr[ni] = *(const bf16x8*)(&Bs[swz(r, g)]);
    }
#pragma unroll
    for (int mi = 0; mi < 4; ++mi)
#pragma unroll
      for (int ni = 0; ni < 4; ++ni)
        acc[mi][ni] = __builtin_amdgcn_mfma_f32_16x16x32_bf16(af[mi], bfr[ni], acc[mi][ni], 0, 0, 0);
    __syncthreads();
  }

  const int bb = m0 >> 11;
  float qpv[4], vv[4];
#pragma unroll
  for (int ni = 0; ni < 4; ++ni) {
    int h = n0 + wn * 64 + ni * 16 + (lane & 15);
    qpv[ni] = qp[bb * H_ + h];
    vv[ni]  = v[h];
  }
#pragma unroll
  for (int mi = 0; mi < 4; ++mi) {
    float ps[4] = {0.f, 0.f, 0.f, 0.f};
#pragma unroll
    for (int ni = 0; ni < 4; ++ni)
#pragma unroll
      for (int rr = 0; rr < 4; ++rr)
        ps[rr] += fast_tanh(acc[mi][ni][rr] + qpv[ni]) * vv[ni];
#pragma unroll
    for (int off = 1; off < 16; off <<= 1)
#pragma unroll
      for (int rr = 0; rr < 4; ++rr)
        ps[rr] += __shfl_xor(ps[rr], off, 64);
    if ((lane & 15) == 0) {
      int rowbase = m0 + wm * 64 + mi * 16 + (lane >> 4) * 4;
#pragma unroll
      for (int rr = 0; rr < 4; ++rr)
        atomicAdd(&energy[rowbase + rr], ps[rr]);
    }
  }
}

// ---------------------------------------------------------------- masked softmax
__global__ void softmax_kernel(const float* __restrict__ energy, const void* __restrict__ mask,
                               const int* __restrict__ flag, float* __restrict__ attn) {
  __shared__ float red[256];
  const int b = blockIdx.x, t = threadIdx.x;
  const int fl = flag[0];
  float e[8];
#pragma unroll
  for (int i = 0; i < 8; ++i) {
    int idx = b * S_ + i * 256 + t;
    e[i] = mask_at(mask, fl, idx) ? -INFINITY : energy[idx];
  }
  float mx = e[0];
#pragma unroll
  for (int i = 1; i < 8; ++i) mx = fmaxf(mx, e[i]);
  red[t] = mx; __syncthreads();
  for (int o = 128; o > 0; o >>= 1) { if (t < o) red[t] = fmaxf(red[t], red[t + o]); __syncthreads(); }
  mx = red[0];
  __syncthreads();
  const bool any = (mx > -INFINITY);
  float p[8]; float sum = 0.f;
#pragma unroll
  for (int i = 0; i < 8; ++i) {
    p[i] = (any && e[i] > -INFINITY) ? __expf(e[i] - mx) : 0.f;
    sum += p[i];
  }
  red[t] = sum; __syncthreads();
  for (int o = 128; o > 0; o >>= 1) { if (t < o) red[t] += red[t + o]; __syncthreads(); }
  sum = red[0];
  const float inv = (sum > 0.f) ? 1.f / sum : 0.f;
#pragma unroll
  for (int i = 0; i < 8; ++i) attn[b * S_ + i * 256 + t] = p[i] * inv;
}

// ---------------------------------------------------------------- context, per-(batch,chunk)
__global__ void context_gb(const float* __restrict__ attn, const float* __restrict__ keys,
                           const int* __restrict__ misc, const int* __restrict__ ridx,
                           float* __restrict__ ctx) {
  const int b = blockIdx.y, chunk = blockIdx.x;
  const int jb = misc[144 + 2 * b];
  const int je = misc[144 + 2 * b + 2];     // sentinel at [144+128] covers b=63
  const int j0 = jb + chunk * 64;
  if (j0 >= je) return;
  const int j1 = (j0 + 64 < je) ? j0 + 64 : je;
  const int t = threadIdx.x;                 // k = 4t..4t+3
  float4 acc = {0.f, 0.f, 0.f, 0.f};
#pragma unroll 4
  for (int j = j0; j < j1; ++j) {
    const int row = ridx[j];
    const float a = attn[row];
    float4 kv = *(const float4*)(keys + (size_t)row * K_ + t * 4);
    acc.x += a * kv.x; acc.y += a * kv.y; acc.z += a * kv.z; acc.w += a * kv.w;
  }
  float* cb = ctx + b * K_ + t * 4;
  atomicAdd(cb + 0, acc.x); atomicAdd(cb + 1, acc.y);
  atomicAdd(cb + 2, acc.z); atomicAdd(cb + 3, acc.w);
}

// ---------------------------------------------------------------- fallback context (dense f32)
__global__ void context_kernel(const float* __restrict__ attn, const float* __restrict__ keys,
                               float* __restrict__ ctx) {
  const int b = blockIdx.y;
  const int sc = blockIdx.x;
  const int t = threadIdx.x;
  const float* kb = keys + ((size_t)b * S_ + sc * 128) * K_;
  const float* ab = attn + b * S_ + sc * 128;
  float4 acc = {0.f, 0.f, 0.f, 0.f};
  for (int s = 0; s < 128; ++s) {
    float a = ab[s];
    if (a != 0.f) {
      float4 kv = *(const float4*)(kb + (size_t)s * K_ + t * 4);
      acc.x += a * kv.x; acc.y += a * kv.y; acc.z += a * kv.z; acc.w += a * kv.w;
    }
  }
  float* cb = ctx + b * K_ + t * 4;
  atomicAdd(cb + 0, acc.x);
  atomicAdd(cb + 1, acc.y);
  atomicAdd(cb + 2, acc.z);
  atomicAdd(cb + 3, acc.w);
}

// ---------------------------------------------------------------- launch
extern "C" void kernel_launch(void* const* d_in, const int* in_sizes, int n_in,
                              void* d_out, int out_size, void* d_ws, size_t ws_size,
                              hipStream_t stream) {
  (void)in_sizes; (void)n_in; (void)out_size;
  const float* query = (const float*)d_in[0];
  const float* keys  = (const float*)d_in[1];
  const void*  mask  = d_in[2];
  const float* Wq    = (const float*)d_in[3];
  const float* Wk    = (const float*)d_in[4];
  const float* v     = (const float*)d_in[5];

  float* ctx  = (float*)d_out;             // [64][1024]
  float* attn = (float*)d_out + B_ * K_;   // [64][2048]

  char* ws = (char*)d_ws;
  float*          energy = (float*)ws;                              // 512 KiB
  float*          qp     = (float*)(ws + (512 << 10));              // 256 KiB
  unsigned short* wkb    = (unsigned short*)(ws + (768 << 10));     // 2 MiB
  int*            misc   = (int*)(ws + (768 << 10) + (2 << 20));    // 4 KiB
  int*            ridx   = (int*)(ws + (3 << 20));                  // 512 KiB

  const bool big = ws_size >= (size_t)(4 << 20);

  hipMemsetAsync(energy, 0, (size_t)M_ * 4, stream);
  hipMemsetAsync(ctx, 0, (size_t)B_ * K_ * 4, stream);
  detect_mask<<<1, 256, 0, stream>>>((const unsigned int*)mask, misc);
  convert_wk<<<(H_ * K_ / 4) / 256, 256, 0, stream>>>(Wk, wkb);
  qp_kernel<<<dim3(4, B_), 256, 0, stream>>>(query, Wq, qp);
  if (big) {
    mask_count<<<128, 256, 0, stream>>>(mask, misc);
    mask_scan<<<1, 64, 0, stream>>>(misc);
    mask_writeidx<<<128, 256, 0, stream>>>(mask, misc, ridx);
    gemm_energy_g<<<(M_ / 128) * (H_ / 128), 256, 0, stream>>>(
        keys, (const __bf16*)wkb, qp, v, energy, misc, ridx);
    softmax_kernel<<<B_, 256, 0, stream>>>(energy, mask, misc, attn);
    context_gb<<<dim3(32, B_), 256, 0, stream>>>(attn, keys, misc, ridx, ctx);
  } else {
    gemm_energy<<<(M_ / 128) * (H_ / 128), 256, 0, stream>>>(
        keys, (const __bf16*)wkb, qp, v, energy);
    softmax_kernel<<<B_, 256, 0, stream>>>(energy, mask, misc, attn);
    context_kernel<<<dim3(S_ / 128, B_), 256, 0, stream>>>(attn, keys, ctx);
  }
}

// Round 14
// 335.061 us; speedup vs baseline: 1.2653x; 1.2653x over previous
//
#include <hip/hip_runtime.h>
#include <math.h>

#define B_ 64
#define S_ 2048
#define H_ 1024
#define K_ 1024
#define M_ (B_*S_)   // 131072 rows of the big GEMM

using f32x4   = __attribute__((ext_vector_type(4))) float;
using bf16x8  = __attribute__((ext_vector_type(8))) __bf16;

__device__ __forceinline__ unsigned short f2b(float f) {
  unsigned int u = __float_as_uint(f);
  u += 0x7fffu + ((u >> 16) & 1u);   // RNE
  return (unsigned short)(u >> 16);
}

// tanh(x) = (e^2x - 1)/(e^2x + 1); clamp so t stays finite (tanh saturated anyway)
__device__ __forceinline__ float fast_tanh(float x) {
  float xc = fminf(fmaxf(x, -15.f), 15.f);
  float t = __expf(2.f * xc);
  return (t - 1.f) * __builtin_amdgcn_rcpf(t + 1.f);
}

typedef __attribute__((address_space(1))) void gvoid_t;
typedef __attribute__((address_space(3))) void lvoid_t;

__device__ __forceinline__ void async16(const void* g, void* l) {
  __builtin_amdgcn_global_load_lds((gvoid_t*)g, (lvoid_t*)l, 16, 0, 0);
}

// ---- BK=64 tile swizzles (both-sides; R13 post-mortem: full 8-spread -> 2-way=free)
// A f32 [128][64]: 16 chunks of 16B per row; chunk' = chunk ^ (r&7)
// bank group = chunk' mod 8 -> all 8 distinct across r&7 -> 2 lanes/group (free)
__device__ __forceinline__ int swzf64(int r, int chunk) {
  return r * 64 + ((chunk ^ (r & 7)) << 2);   // f32 elements
}
// B bf16 [128][64]: 8 slots of 16B per row; slot' = sl ^ (r&7) (already 8-spread)
__device__ __forceinline__ int swzb64(int r, int sl) {
  return r * 64 + ((sl ^ (r & 7)) << 3);             // bf16 elements
}
// legacy 32-wide swizzle for the fallback kernel
__device__ __forceinline__ int swz(int r, int sl) {
  return r * 32 + ((sl ^ ((r >> 1) & 3)) << 3);
}

// mask decode shared by all mask readers
__device__ __forceinline__ bool mask_at(const void* mask, int fl, int idx) {
  if (fl == 1)      return ((const unsigned char*)mask)[idx] != 0;
  else if (fl == 2) return ((const float*)mask)[idx] != 0.f;
  else              return ((const int*)mask)[idx] != 0;
}

// misc layout (ints): [0]=flag [1]=Mp [2]=Mpr(128-rounded)
//                     [16..144)=blocksum  [144..272]=blockoff (272 = Mp sentinel)

// ---------------------------------------------------------------- mask dtype
__global__ void detect_mask(const unsigned int* __restrict__ m, int* __restrict__ misc) {
  __shared__ int red[256];
  int t = threadIdx.x;
  int f = 0;
  for (int i = 0; i < 32; ++i) {
    unsigned int w = m[t * 32 + i];
    if (w > 1u) f |= 1;
    if (w != 0u && w != 0x3f800000u) f |= 2;
  }
  red[t] = f;
  __syncthreads();
  for (int o = 128; o > 0; o >>= 1) { if (t < o) red[t] |= red[t + o]; __syncthreads(); }
  if (t == 0) {
    int g = red[0];
    misc[0] = ((g & 1) == 0) ? 0 : (((g & 2) == 0) ? 2 : 1);
  }
}

// ---------------------------------------------------------------- compaction scans
__global__ void mask_count(const void* __restrict__ mask, int* __restrict__ misc) {
  __shared__ int red[256];
  const int fl = misc[0];
  const int t = threadIdx.x, blk = blockIdx.x;
  int cnt = 0;
#pragma unroll
  for (int i = 0; i < 4; ++i)
    cnt += mask_at(mask, fl, blk * 1024 + t * 4 + i) ? 0 : 1;
  red[t] = cnt; __syncthreads();
  for (int o = 128; o > 0; o >>= 1) { if (t < o) red[t] += red[t + o]; __syncthreads(); }
  if (t == 0) misc[16 + blk] = red[0];
}

__global__ void mask_scan(int* __restrict__ misc) {
  if (threadIdx.x == 0) {
    int acc = 0;
    for (int i = 0; i < 128; ++i) { misc[144 + i] = acc; acc += misc[16 + i]; }
    misc[144 + 128] = acc;    // sentinel: end of batch 63
    misc[1] = acc;
    misc[2] = (acc + 127) & ~127;
  }
}

__global__ void mask_writeidx(const void* __restrict__ mask, const int* __restrict__ misc,
                              int* __restrict__ ridx) {
  __shared__ int sc[256];
  const int fl = misc[0];
  const int t = threadIdx.x, blk = blockIdx.x;
  int um[4]; int cnt = 0;
#pragma unroll
  for (int i = 0; i < 4; ++i) {
    um[i] = mask_at(mask, fl, blk * 1024 + t * 4 + i) ? 0 : 1;
    cnt += um[i];
  }
  sc[t] = cnt; __syncthreads();
  for (int o = 1; o < 256; o <<= 1) {
    int v = (t >= o) ? sc[t - o] : 0;
    __syncthreads();
    sc[t] += v;
    __syncthreads();
  }
  int base = misc[144 + blk] + sc[t] - cnt;   // exclusive prefix
#pragma unroll
  for (int i = 0; i < 4; ++i)
    if (um[i]) ridx[base++] = blk * 1024 + t * 4 + i;
}

// ---------------------------------------------------------------- Wk -> bf16
__global__ void convert_wk(const float* __restrict__ src, unsigned short* __restrict__ dst) {
  int i = blockIdx.x * blockDim.x + threadIdx.x;
  float4 v = ((const float4*)src)[i];
  ushort4 o;
  o.x = f2b(v.x); o.y = f2b(v.y); o.z = f2b(v.z); o.w = f2b(v.w);
  *(ushort4*)(dst + (size_t)i * 4) = o;
}

// ---------------------------------------------------------------- qp = query @ Wq.T
__global__ void qp_kernel(const float* __restrict__ query, const float* __restrict__ Wq,
                          float* __restrict__ qp) {
  __shared__ float qs[1024];
  const int b = blockIdx.y, q4b = blockIdx.x, t = threadIdx.x;
  ((float4*)qs)[t] = ((const float4*)(query + b * 1024))[t];
  __syncthreads();
  const int h = q4b * 256 + t;
  const float4* wr = (const float4*)(Wq + (size_t)h * 1024);
  float s = 0.f;
#pragma unroll 4
  for (int q4 = 0; q4 < 256; ++q4) {
    float4 w = wr[q4];
    float4 q = ((const float4*)qs)[q4];
    s += w.x * q.x + w.y * q.y + w.z * q.z + w.w * q.w;
  }
  qp[b * 1024 + h] = s;
}

// ---------------------------------------------------------------- GEMM+energy, gather f32 A, BK=64
// R12 structure (best: single-buffer, 2 barriers/step, 16 steps) with the A-read
// bank spread fixed: chunk' = chunk ^ (r&7) (was ^((r&7)<<1), a 4-way conflict);
// lo/hi halves read as two separately-swizzled ds_read_b128.
__global__ __launch_bounds__(256, 3) void gemm_energy_g(
    const float* __restrict__ keys,          // [M_][1024] f32 (original)
    const __bf16* __restrict__ wk,           // [1024][1024] bf16 Wk
    const float* __restrict__ qp,            // [64][1024]
    const float* __restrict__ v,             // [1024]
    float* __restrict__ energy,              // [M_] (original row ids)
    const int* __restrict__ misc,
    const int* __restrict__ ridx) {
  __shared__ __align__(16) float  Asf[128 * 64];   // 32 KB
  __shared__ __align__(16) __bf16 Bs[128 * 64];    // 16 KB

  const int tid  = threadIdx.x;
  const int w    = tid >> 6;
  const int lane = tid & 63;

  // XCD mapping (R9-proven): all 8 n-tiles of an m-tile on one XCD; working
  // m-tiles spread over all XCDs regardless of compact count.
  const int orig = blockIdx.x;                   // 0..8191
  const int x = orig & 7, j = orig >> 3;
  const int m0 = (x + 8 * (j >> 3)) * 128;
  const int n0 = (j & 7) * 128;

  const int mpr = misc[2];
  const int mp  = misc[1];
  if (m0 >= mpr || mp == 0) return;

  const int wm = w >> 1, wn = w & 1;

  f32x4 acc[4][4] = {};

  // A staging: [128][64] f32 = 2048 chunks of 16B; this thread owns 8.
  int aoff[8];
#pragma unroll
  for (int i = 0; i < 8; ++i) {
    int c = tid + i * 256;
    int r = c >> 4, chunk = c & 15;
    int row = m0 + r;
    int oro = (row < mp) ? ridx[row] : ridx[mp - 1];   // clamp: pads discarded later
    aoff[i] = oro * K_ + ((chunk ^ (r & 7)) << 2);     // source pre-swizzled (matches swzf64)
  }
  // B staging: [128][64] bf16 = 1024 chunks of 16B; this thread owns 4.
  int boff[4];
#pragma unroll
  for (int jj = 0; jj < 4; ++jj) {
    int c = tid + jj * 256;
    int r = c >> 3, sl = c & 7;
    boff[jj] = (n0 + r) * K_ + ((sl ^ (r & 7)) << 3);
  }

  for (int kt = 0; kt < 16; ++kt) {
    const int k0 = kt * 64;
#pragma unroll
    for (int i = 0; i < 8; ++i)
      async16(keys + (size_t)aoff[i] + k0, &Asf[(i * 256 + w * 64) * 4]);
#pragma unroll
    for (int jj = 0; jj < 4; ++jj)
      async16(wk + (size_t)boff[jj] + k0, &Bs[(jj * 256 + w * 64) * 8]);
    __syncthreads();
    const int g = lane >> 4;
#pragma unroll
    for (int ks = 0; ks < 2; ++ks) {
      bf16x8 af[4], bfr[4];
#pragma unroll
      for (int mi = 0; mi < 4; ++mi) {
        int r = wm * 64 + mi * 16 + (lane & 15);
        f32x4 lo = *(const f32x4*)(&Asf[swzf64(r, ks * 8 + g * 2)]);
        f32x4 hi = *(const f32x4*)(&Asf[swzf64(r, ks * 8 + g * 2 + 1)]);
        bf16x8 u;
        u[0] = (__bf16)lo[0]; u[1] = (__bf16)lo[1]; u[2] = (__bf16)lo[2]; u[3] = (__bf16)lo[3];
        u[4] = (__bf16)hi[0]; u[5] = (__bf16)hi[1]; u[6] = (__bf16)hi[2]; u[7] = (__bf16)hi[3];
        af[mi] = u;
      }
#pragma unroll
      for (int ni = 0; ni < 4; ++ni) {
        int r = wn * 64 + ni * 16 + (lane & 15);
        bfr[ni] = *(const bf16x8*)(&Bs[swzb64(r, ks * 4 + g)]);
      }
#pragma unroll
      for (int mi = 0; mi < 4; ++mi)
#pragma unroll
        for (int ni = 0; ni < 4; ++ni)
          acc[mi][ni] = __builtin_amdgcn_mfma_f32_16x16x32_bf16(af[mi], bfr[ni], acc[mi][ni], 0, 0, 0);
    }
    __syncthreads();
  }

  // epilogue with ridx indirection
  float vv[4]; int hh[4];
#pragma unroll
  for (int ni = 0; ni < 4; ++ni) {
    hh[ni] = n0 + wn * 64 + ni * 16 + (lane & 15);
    vv[ni] = v[hh[ni]];
  }
#pragma unroll
  for (int mi = 0; mi < 4; ++mi) {
    const int rowbase = m0 + wm * 64 + mi * 16 + (lane >> 4) * 4;
    int oro[4];
#pragma unroll
    for (int rr = 0; rr < 4; ++rr) {
      int row = rowbase + rr;
      oro[rr] = (row < mp) ? ridx[row] : -1;
    }
    float ps[4] = {0.f, 0.f, 0.f, 0.f};
#pragma unroll
    for (int ni = 0; ni < 4; ++ni)
#pragma unroll
      for (int rr = 0; rr < 4; ++rr) {
        int bb = (oro[rr] >= 0 ? oro[rr] : 0) >> 11;
        ps[rr] += fast_tanh(acc[mi][ni][rr] + qp[bb * H_ + hh[ni]]) * vv[ni];
      }
#pragma unroll
    for (int off = 1; off < 16; off <<= 1)
#pragma unroll
      for (int rr = 0; rr < 4; ++rr)
        ps[rr] += __shfl_xor(ps[rr], off, 64);
    if ((lane & 15) == 0) {
#pragma unroll
      for (int rr = 0; rr < 4; ++rr)
        if (oro[rr] >= 0) atomicAdd(&energy[oro[rr]], ps[rr]);
    }
  }
}

// ---------------------------------------------------------------- fallback GEMM (f32 keys, full M)
__global__ __launch_bounds__(256) void gemm_energy(
    const float* __restrict__ keys, const __bf16* __restrict__ wk,
    const float* __restrict__ qp, const float* __restrict__ v,
    float* __restrict__ energy) {
  __shared__ __align__(16) __bf16 As[128 * 32];
  __shared__ __align__(16) __bf16 Bs[128 * 32];

  const int tid  = threadIdx.x;
  const int w    = tid >> 6;
  const int lane = tid & 63;

  const int orig = blockIdx.x;
  const int wgid = (orig & 7) * 1024 + (orig >> 3);
  const int m0 = (wgid >> 3) * 128;
  const int n0 = (wgid & 7) * 128;

  const int wm = w >> 1, wn = w & 1;

  f32x4 acc[4][4] = {};

  int arow[2], aslot[2];
#pragma unroll
  for (int i = 0; i < 2; ++i) {
    int c = tid + i * 256;
    arow[i]  = c >> 2;
    aslot[i] = c & 3;
  }
  const float* Abase = keys + (size_t)m0 * K_;

  int brow[2], bs_src[2], bs_dst[2];
#pragma unroll
  for (int j = 0; j < 2; ++j) {
    int flat = w * 1024 + j * 512 + lane * 8;
    brow[j]   = flat >> 5;
    bs_src[j] = (((flat >> 3) & 3) ^ ((brow[j] >> 1) & 3)) * 8;
    bs_dst[j] = w * 1024 + j * 512;
  }

  float4 pre[2][2];
#pragma unroll
  for (int i = 0; i < 2; ++i) {
    const float* p = Abase + arow[i] * K_ + aslot[i] * 8;
    pre[i][0] = *(const float4*)p;
    pre[i][1] = *(const float4*)(p + 4);
  }

  for (int kt = 0; kt < 32; ++kt) {
    const int k0 = kt * 32;
#pragma unroll
    for (int i = 0; i < 2; ++i) {
      bf16x8 u;
      u[0] = (__bf16)pre[i][0].x; u[1] = (__bf16)pre[i][0].y;
      u[2] = (__bf16)pre[i][0].z; u[3] = (__bf16)pre[i][0].w;
      u[4] = (__bf16)pre[i][1].x; u[5] = (__bf16)pre[i][1].y;
      u[6] = (__bf16)pre[i][1].z; u[7] = (__bf16)pre[i][1].w;
      *(bf16x8*)(&As[swz(arow[i], aslot[i])]) = u;
    }
#pragma unroll
    for (int j = 0; j < 2; ++j)
      async16(wk + (size_t)(n0 + brow[j]) * K_ + k0 + bs_src[j], &Bs[bs_dst[j]]);
    __syncthreads();
    if (kt + 1 < 32) {
#pragma unroll
      for (int i = 0; i < 2; ++i) {
        const float* p = Abase + arow[i] * K_ + (k0 + 32) + aslot[i] * 8;
        pre[i][0] = *(const float4*)p;
        pre[i][1] = *(const float4*)(p + 4);
      }
    }
    const int g = lane >> 4;
    bf16x8 af[4], bfr[4];
#pragma unroll
    for (int mi = 0; mi < 4; ++mi) {
      int r = wm * 64 + mi * 16 + (lane & 15);
      af[mi] = *(const bf16x8*)(&As[swz(r, g)]);
    }
#pragma unroll
    for (int ni = 0; ni < 4; ++ni) {
      int r = wn * 64 + ni * 16 + (lane & 15);
      bfr[ni] = *(const bf16x8*)(&Bs[swz(r, g)]);
    }
#pragma unroll
    for (int mi = 0; mi < 4; ++mi)
#pragma unroll
      for (int ni = 0; ni < 4; ++ni)
        acc[mi][ni] = __builtin_amdgcn_mfma_f32_16x16x32_bf16(af[mi], bfr[ni], acc[mi][ni], 0, 0, 0);
    __syncthreads();
  }

  const int bb = m0 >> 11;
  float qpv[4], vv[4];
#pragma unroll
  for (int ni = 0; ni < 4; ++ni) {
    int h = n0 + wn * 64 + ni * 16 + (lane & 15);
    qpv[ni] = qp[bb * H_ + h];
    vv[ni]  = v[h];
  }
#pragma unroll
  for (int mi = 0; mi < 4; ++mi) {
    float ps[4] = {0.f, 0.f, 0.f, 0.f};
#pragma unroll
    for (int ni = 0; ni < 4; ++ni)
#pragma unroll
      for (int rr = 0; rr < 4; ++rr)
        ps[rr] += fast_tanh(acc[mi][ni][rr] + qpv[ni]) * vv[ni];
#pragma unroll
    for (int off = 1; off < 16; off <<= 1)
#pragma unroll
      for (int rr = 0; rr < 4; ++rr)
        ps[rr] += __shfl_xor(ps[rr], off, 64);
    if ((lane & 15) == 0) {
      int rowbase = m0 + wm * 64 + mi * 16 + (lane >> 4) * 4;
#pragma unroll
      for (int rr = 0; rr < 4; ++rr)
        atomicAdd(&energy[rowbase + rr], ps[rr]);
    }
  }
}

// ---------------------------------------------------------------- masked softmax
__global__ void softmax_kernel(const float* __restrict__ energy, const void* __restrict__ mask,
                               const int* __restrict__ flag, float* __restrict__ attn) {
  __shared__ float red[256];
  const int b = blockIdx.x, t = threadIdx.x;
  const int fl = flag[0];
  float e[8];
#pragma unroll
  for (int i = 0; i < 8; ++i) {
    int idx = b * S_ + i * 256 + t;
    e[i] = mask_at(mask, fl, idx) ? -INFINITY : energy[idx];
  }
  float mx = e[0];
#pragma unroll
  for (int i = 1; i < 8; ++i) mx = fmaxf(mx, e[i]);
  red[t] = mx; __syncthreads();
  for (int o = 128; o > 0; o >>= 1) { if (t < o) red[t] = fmaxf(red[t], red[t + o]); __syncthreads(); }
  mx = red[0];
  __syncthreads();
  const bool any = (mx > -INFINITY);
  float p[8]; float sum = 0.f;
#pragma unroll
  for (int i = 0; i < 8; ++i) {
    p[i] = (any && e[i] > -INFINITY) ? __expf(e[i] - mx) : 0.f;
    sum += p[i];
  }
  red[t] = sum; __syncthreads();
  for (int o = 128; o > 0; o >>= 1) { if (t < o) red[t] += red[t + o]; __syncthreads(); }
  sum = red[0];
  const float inv = (sum > 0.f) ? 1.f / sum : 0.f;
#pragma unroll
  for (int i = 0; i < 8; ++i) attn[b * S_ + i * 256 + t] = p[i] * inv;
}

// ---------------------------------------------------------------- context, per-(batch,chunk)
__global__ void context_gb(const float* __restrict__ attn, const float* __restrict__ keys,
                           const int* __restrict__ misc, const int* __restrict__ ridx,
                           float* __restrict__ ctx) {
  const int b = blockIdx.y, chunk = blockIdx.x;
  const int jb = misc[144 + 2 * b];
  const int je = misc[144 + 2 * b + 2];     // sentinel at [144+128] covers b=63
  const int j0 = jb + chunk * 64;
  if (j0 >= je) return;
  const int j1 = (j0 + 64 < je) ? j0 + 64 : je;
  const int t = threadIdx.x;                 // k = 4t..4t+3
  float4 acc = {0.f, 0.f, 0.f, 0.f};
#pragma unroll 4
  for (int j = j0; j < j1; ++j) {
    const int row = ridx[j];
    const float a = attn[row];
    float4 kv = *(const float4*)(keys + (size_t)row * K_ + t * 4);
    acc.x += a * kv.x; acc.y += a * kv.y; acc.z += a * kv.z; acc.w += a * kv.w;
  }
  float* cb = ctx + b * K_ + t * 4;
  atomicAdd(cb + 0, acc.x); atomicAdd(cb + 1, acc.y);
  atomicAdd(cb + 2, acc.z); atomicAdd(cb + 3, acc.w);
}

// ---------------------------------------------------------------- fallback context (dense f32)
__global__ void context_kernel(const float* __restrict__ attn, const float* __restrict__ keys,
                               float* __restrict__ ctx) {
  const int b = blockIdx.y;
  const int sc = blockIdx.x;
  const int t = threadIdx.x;
  const float* kb = keys + ((size_t)b * S_ + sc * 128) * K_;
  const float* ab = attn + b * S_ + sc * 128;
  float4 acc = {0.f, 0.f, 0.f, 0.f};
  for (int s = 0; s < 128; ++s) {
    float a = ab[s];
    if (a != 0.f) {
      float4 kv = *(const float4*)(kb + (size_t)s * K_ + t * 4);
      acc.x += a * kv.x; acc.y += a * kv.y; acc.z += a * kv.z; acc.w += a * kv.w;
    }
  }
  float* cb = ctx + b * K_ + t * 4;
  atomicAdd(cb + 0, acc.x);
  atomicAdd(cb + 1, acc.y);
  atomicAdd(cb + 2, acc.z);
  atomicAdd(cb + 3, acc.w);
}

// ---------------------------------------------------------------- launch
extern "C" void kernel_launch(void* const* d_in, const int* in_sizes, int n_in,
                              void* d_out, int out_size, void* d_ws, size_t ws_size,
                              hipStream_t stream) {
  (void)in_sizes; (void)n_in; (void)out_size;
  const float* query = (const float*)d_in[0];
  const float* keys  = (const float*)d_in[1];
  const void*  mask  = d_in[2];
  const float* Wq    = (const float*)d_in[3];
  const float* Wk    = (const float*)d_in[4];
  const float* v     = (const float*)d_in[5];

  float* ctx  = (float*)d_out;             // [64][1024]
  float* attn = (float*)d_out + B_ * K_;   // [64][2048]

  char* ws = (char*)d_ws;
  float*          energy = (float*)ws;                              // 512 KiB
  float*          qp     = (float*)(ws + (512 << 10));              // 256 KiB
  unsigned short* wkb    = (unsigned short*)(ws + (768 << 10));     // 2 MiB
  int*            misc   = (int*)(ws + (768 << 10) + (2 << 20));    // 4 KiB
  int*            ridx   = (int*)(ws + (3 << 20));                  // 512 KiB

  const bool big = ws_size >= (size_t)(4 << 20);

  hipMemsetAsync(energy, 0, (size_t)M_ * 4, stream);
  hipMemsetAsync(ctx, 0, (size_t)B_ * K_ * 4, stream);
  detect_mask<<<1, 256, 0, stream>>>((const unsigned int*)mask, misc);
  convert_wk<<<(H_ * K_ / 4) / 256, 256, 0, stream>>>(Wk, wkb);
  qp_kernel<<<dim3(4, B_), 256, 0, stream>>>(query, Wq, qp);
  if (big) {
    mask_count<<<128, 256, 0, stream>>>(mask, misc);
    mask_scan<<<1, 64, 0, stream>>>(misc);
    mask_writeidx<<<128, 256, 0, stream>>>(mask, misc, ridx);
    gemm_energy_g<<<(M_ / 128) * (H_ / 128), 256, 0, stream>>>(
        keys, (const __bf16*)wkb, qp, v, energy, misc, ridx);
    softmax_kernel<<<B_, 256, 0, stream>>>(energy, mask, misc, attn);
    context_gb<<<dim3(32, B_), 256, 0, stream>>>(attn, keys, misc, ridx, ctx);
  } else {
    gemm_energy<<<(M_ / 128) * (H_ / 128), 256, 0, stream>>>(
        keys, (const __bf16*)wkb, qp, v, energy);
    softmax_kernel<<<B_, 256, 0, stream>>>(energy, mask, misc, attn);
    context_kernel<<<dim3(S_ / 128, B_), 256, 0, stream>>>(attn, keys, ctx);
  }
}